// Round 6
// baseline (303.657 us; speedup 1.0000x reference)
//
#include <hip/hip_runtime.h>
#include <hip/hip_bf16.h>

#define B_   2048
#define N_   1024
#define BETA 0.001f
#define VAR_MIN 1e-7f

#define PTS   256              // points per stage
#define NSTG  (N_ / PTS)       // 4 stages
#define ROWF  520              // floats per LDS row: 256*2 + 8 pad (2080 B, 16B-aligned)

typedef __attribute__((ext_vector_type(8))) short  bf16x8;
typedef __attribute__((ext_vector_type(4))) float  f32x4;

__device__ __forceinline__ unsigned short f2bf_u(float x) {
    __hip_bfloat16 h = __float2bfloat16(x);
    return __builtin_bit_cast(unsigned short, h);
}
__device__ __forceinline__ float softplus_fast(float x) {
    return x > 20.f ? x : log1pf(__expf(x));
}
__device__ __forceinline__ float softplus_ref(float x) {
    return x > 20.f ? x : log1pf(expf(x));
}

// pi(k): contraction-position permutation letting the previous layer's
// C-layout registers feed the next MFMA's B positions with zero cross-lane
// movement (verified absmax 0.0 in R4/R5).
__device__ __forceinline__ int kperm(int k) {
    return 4 * (k >> 3) + (k & 3) + 16 * ((k >> 2) & 1);
}

// A-frag weight prep (one 64-thread block, runs once per launch).
extern "C" __global__ void hib_prep(const float* __restrict__ W1,
                                    const float* __restrict__ W2,
                                    const float* __restrict__ Wmu,
                                    const float* __restrict__ Wv,
                                    unsigned short* __restrict__ wf)
{
    const int l = threadIdx.x;         // 0..63
    const int r = l & 15, kb = l >> 4;
#pragma unroll
    for (int j = 0; j < 8; j++) {
        const int k1 = kb * 8 + j;
        const int kp = kperm(k1);
        wf[(0 * 64 + l) * 8 + j] = f2bf_u(W1[k1 * 32 + r]);
        wf[(1 * 64 + l) * 8 + j] = f2bf_u(W1[k1 * 32 + 16 + r]);
        wf[(2 * 64 + l) * 8 + j] = f2bf_u(W2[kp * 32 + r]);
        wf[(3 * 64 + l) * 8 + j] = f2bf_u(W2[kp * 32 + 16 + r]);
        wf[(4 * 64 + l) * 8 + j] = f2bf_u(r < 8 ? Wmu[kp * 8 + r]
                                                : Wv[kp * 8 + (r - 8)]);
    }
}

__device__ __forceinline__ bf16x8 pack_relu(f32x4 a, f32x4 b) {
    bf16x8 o;
    o[0] = (short)f2bf_u(fmaxf(a.x, 0.f));
    o[1] = (short)f2bf_u(fmaxf(a.y, 0.f));
    o[2] = (short)f2bf_u(fmaxf(a.z, 0.f));
    o[3] = (short)f2bf_u(fmaxf(a.w, 0.f));
    o[4] = (short)f2bf_u(fmaxf(b.x, 0.f));
    o[5] = (short)f2bf_u(fmaxf(b.y, 0.f));
    o[6] = (short)f2bf_u(fmaxf(b.z, 0.f));
    o[7] = (short)f2bf_u(fmaxf(b.w, 0.f));
    return o;
}

__device__ __forceinline__ void point_chain(
    const float (&x)[8],
    bf16x8 A1a, bf16x8 A1b, bf16x8 A2a, bf16x8 A2b, bf16x8 Ahd,
    f32x4 c1a, f32x4 c1b, f32x4 c2a, f32x4 c2b, f32x4 chd,
    bool is_v, f32x4& acc)
{
    bf16x8 bx;
#pragma unroll
    for (int j = 0; j < 8; j++) bx[j] = (short)f2bf_u(x[j]);
    f32x4 d1a = __builtin_amdgcn_mfma_f32_16x16x32_bf16(A1a, bx, c1a, 0, 0, 0);
    f32x4 d1b = __builtin_amdgcn_mfma_f32_16x16x32_bf16(A1b, bx, c1b, 0, 0, 0);
    bf16x8 b2 = pack_relu(d1a, d1b);
    f32x4 d2a = __builtin_amdgcn_mfma_f32_16x16x32_bf16(A2a, b2, c2a, 0, 0, 0);
    f32x4 d2b = __builtin_amdgcn_mfma_f32_16x16x32_bf16(A2b, b2, c2b, 0, 0, 0);
    bf16x8 b3 = pack_relu(d2a, d2b);
    f32x4 e   = __builtin_amdgcn_mfma_f32_16x16x32_bf16(Ahd, b3, chd, 0, 0, 0);
    if (!is_v) {
        acc.x += e.x; acc.y += e.y; acc.z += e.z; acc.w += e.w;
    } else {
        acc.x += 1.f / fmaxf(softplus_fast(e.x), VAR_MIN);
        acc.y += 1.f / fmaxf(softplus_fast(e.y), VAR_MIN);
        acc.z += 1.f / fmaxf(softplus_fast(e.z), VAR_MIN);
        acc.w += 1.f / fmaxf(softplus_fast(e.w), VAR_MIN);
    }
}

__device__ __forceinline__ void red16(f32x4& v) {
#pragma unroll
    for (int off = 8; off; off >>= 1) {
        v.x += __shfl_down(v.x, off);
        v.y += __shfl_down(v.y, off);
        v.z += __shfl_down(v.z, off);
        v.w += __shfl_down(v.w, off);
    }
}

// direct global->LDS, 16B per lane; dst is wave-uniform base (lane*16 implicit)
__device__ __forceinline__ void gload_lds16(const float4* gsrc, float* ldst) {
    __builtin_amdgcn_global_load_lds(
        (const __attribute__((address_space(1))) unsigned int*)gsrc,
        (__attribute__((address_space(3))) unsigned int*)ldst,
        16, 0, 0);
}

__global__ void __launch_bounds__(256, 2)
hib_mfma(const float* __restrict__ batch,
         const int* __restrict__ labels,
         const float* __restrict__ eps1, const float* __restrict__ eps2,
         const unsigned short* __restrict__ wf,
         const float* __restrict__ b1, const float* __restrict__ b2,
         const float* __restrict__ bmu, const float* __restrict__ bv,
         const float* __restrict__ sw, const float* __restrict__ sb,
         float* __restrict__ out)
{
    __shared__ float lds[32 * ROWF];   // [row][pt] float2 pairs, padded rows
    __shared__ float sacc[32];

    const int tid = threadIdx.x;
    const int b   = blockIdx.x;
    const int wid = tid >> 6, l = tid & 63;
    const int c   = l & 15, kb = l >> 4;

    if (tid < 32) sacc[tid] = 0.f;

    // weight A-frags, register-resident
    const bf16x8* wfv = (const bf16x8*)wf;
    const bf16x8 A1a = wfv[0 * 64 + l], A1b = wfv[1 * 64 + l];
    const bf16x8 A2a = wfv[2 * 64 + l], A2b = wfv[3 * 64 + l];
    const bf16x8 Ahd = wfv[4 * 64 + l];

    const int r4 = 4 * kb;
    const bool is_v = (kb >= 2);
    const int  z4   = 4 * (kb & 1);
    f32x4 c1a, c1b, c2a, c2b, chd;
    c1a.x = b1[r4];      c1a.y = b1[r4 + 1];      c1a.z = b1[r4 + 2];      c1a.w = b1[r4 + 3];
    c1b.x = b1[16 + r4]; c1b.y = b1[16 + r4 + 1]; c1b.z = b1[16 + r4 + 2]; c1b.w = b1[16 + r4 + 3];
    c2a.x = b2[r4];      c2a.y = b2[r4 + 1];      c2a.z = b2[r4 + 2];      c2a.w = b2[r4 + 3];
    c2b.x = b2[16 + r4]; c2b.y = b2[16 + r4 + 1]; c2b.z = b2[16 + r4 + 2]; c2b.w = b2[16 + r4 + 3];
    if (is_v) { chd.x = bv[z4];  chd.y = bv[z4 + 1];  chd.z = bv[z4 + 2];  chd.w = bv[z4 + 3]; }
    else      { chd.x = bmu[z4]; chd.y = bmu[z4 + 1]; chd.z = bmu[z4 + 2]; chd.w = bmu[z4 + 3]; }

    f32x4 acc0 = {0.f, 0.f, 0.f, 0.f};
    f32x4 acc1 = {0.f, 0.f, 0.f, 0.f};

    // batch[b] as float4: [row r][point-pair p], 512 pairs per row
    const float4* bp4 = (const float4*)batch + (size_t)b * 32 * 512;

#pragma unroll 1
    for (int st = 0; st < NSTG; st++) {
        // ---- stage load: 1KB-contiguous wave instructions, global->LDS ----
        // wave wid owns rows wid*8..wid*8+7; 2 half-KB... 2 instr per row
#pragma unroll
        for (int q = 0; q < 8; q++) {
            const int r = wid * 8 + q;
            const float4* gs = bp4 + (size_t)r * 512 + st * 128 + l;
            gload_lds16(gs,       &lds[r * ROWF]);
            gload_lds16(gs + 64,  &lds[r * ROWF + 256]);
        }
        __syncthreads();   // drains vmcnt: stage resident

        // ---- compute: wave wid handles point-pairs {2wid, 2wid+1} ----
#pragma unroll 1
        for (int pp = 0; pp < 2; pp++) {
            const int pr = wid * 2 + pp;
            float4 xq[8];
#pragma unroll
            for (int j = 0; j < 8; j++)
                xq[j] = *(const float4*)&lds[(kb * 8 + j) * ROWF + pr * 64 + c * 4];

            float xe0[8], xe1[8], xo0[8], xo1[8];
#pragma unroll
            for (int j = 0; j < 8; j++) {
                xe0[j] = xq[j].x; xe1[j] = xq[j].y;
                xo0[j] = xq[j].z; xo1[j] = xq[j].w;
            }
            point_chain(xe0, A1a, A1b, A2a, A2b, Ahd, c1a, c1b, c2a, c2b, chd, is_v, acc0);
            point_chain(xe1, A1a, A1b, A2a, A2b, Ahd, c1a, c1b, c2a, c2b, chd, is_v, acc1);
            point_chain(xo0, A1a, A1b, A2a, A2b, Ahd, c1a, c1b, c2a, c2b, chd, is_v, acc0);
            point_chain(xo1, A1a, A1b, A2a, A2b, Ahd, c1a, c1b, c2a, c2b, chd, is_v, acc1);
        }
        __syncthreads();   // stage buffer free for overwrite
    }

    // ---- reduce over the 16 point-columns in each lane group ----
    red16(acc0);
    red16(acc1);

    if (c == 0) {
        const int base = (is_v ? 16 : 0) + z4;   // +0: ch0, +8: ch1
        atomicAdd(&sacc[base + 0],     acc0.x);
        atomicAdd(&sacc[base + 1],     acc0.y);
        atomicAdd(&sacc[base + 2],     acc0.z);
        atomicAdd(&sacc[base + 3],     acc0.w);
        atomicAdd(&sacc[base + 8 + 0], acc1.x);
        atomicAdd(&sacc[base + 8 + 1], acc1.y);
        atomicAdd(&sacc[base + 8 + 2], acc1.z);
        atomicAdd(&sacc[base + 8 + 3], acc1.w);
    }
    __syncthreads();

    // ---- per-b tail on wave 0: pooling, KL, S x S sampled loss ----
    if (tid < 64) {
        const float a    = softplus_ref(sw[0]);
        const float sbv_ = sb[0];

        float muA[8], muB[8], sgA[8], sgB[8];
#pragma unroll
        for (int z = 0; z < 8; z++) {
            muA[z] = sacc[z];
            muB[z] = sacc[8 + z];
            sgA[z] = sqrtf(1.0f / sacc[16 + z]);
            sgB[z] = sqrtf(1.0f / sacc[24 + z]);
        }
        const int i = tid >> 3, j = tid & 7;
        float d2 = 0.f;
#pragma unroll
        for (int z = 0; z < 8; z++) {
            float e1 = eps1[((size_t)b * 8 + i) * 8 + z];
            float e2 = eps2[((size_t)b * 8 + j) * 8 + z];
            float zz1 = fmaf(sgA[z], e1, muA[z]);
            float zz2 = fmaf(sgB[z], e2, muB[z]);
            float d = zz1 - zz2;
            d2 = fmaf(d, d, d2);
        }
        const float lab = (float)labels[b];
        float contrib = softplus_ref(a * sqrtf(d2) - sbv_) * lab
                      * (1.0f / (64.0f * (float)B_));

        if (tid < 16) {
            const int cc = tid >> 3, z = tid & 7;
            float iv  = sacc[16 + cc * 8 + z];
            float var = 1.0f / iv;
            float m   = sacc[cc * 8 + z];
            contrib += (-0.5f * logf(var) + 0.5f * (var + m * m) - 0.5f)
                       * (BETA / (8.0f * (float)B_));
        }
#pragma unroll
        for (int off = 32; off; off >>= 1) contrib += __shfl_down(contrib, off);
        if (tid == 0) atomicAdd(out, contrib);
    }
}

extern "C" void kernel_launch(void* const* d_in, const int* in_sizes, int n_in,
                              void* d_out, int out_size, void* d_ws, size_t ws_size,
                              hipStream_t stream)
{
    (void)in_sizes; (void)n_in; (void)out_size; (void)ws_size;
    const float* batch  = (const float*)d_in[0];
    const int*   labels = (const int*)  d_in[1];
    const float* eps1   = (const float*)d_in[2];
    const float* eps2   = (const float*)d_in[3];
    const float* W1     = (const float*)d_in[4];
    const float* b1     = (const float*)d_in[5];
    const float* W2     = (const float*)d_in[6];
    const float* b2     = (const float*)d_in[7];
    const float* Wmu    = (const float*)d_in[8];
    const float* bmu    = (const float*)d_in[9];
    const float* Wv     = (const float*)d_in[10];
    const float* bv     = (const float*)d_in[11];
    const float* sw     = (const float*)d_in[12];
    const float* sb     = (const float*)d_in[13];

    unsigned short* wf = (unsigned short*)d_ws;  // 5 frags x 64 lanes x 8 bf16

    hipMemsetAsync(d_out, 0, sizeof(float), stream);
    hib_prep<<<1, 64, 0, stream>>>(W1, W2, Wmu, Wv, wf);
    hib_mfma<<<B_, 256, 0, stream>>>(batch, labels, eps1, eps2, wf,
                                     b1, b2, bmu, bv, sw, sb, (float*)d_out);
}

// Round 8
// 267.754 us; speedup vs baseline: 1.1341x; 1.1341x over previous
//
#include <hip/hip_runtime.h>
#include <hip/hip_bf16.h>

#define B_   2048
#define N_   1024
#define BETA 0.001f
#define VAR_MIN 1e-7f

#define PTS   128              // points per stage
#define NSTG  (N_ / PTS)       // 8 stages
#define ROWF  264              // floats per LDS row: 128*2 + 8 pad

typedef __attribute__((ext_vector_type(8))) short  bf16x8;
typedef __attribute__((ext_vector_type(4))) float  f32x4;

__device__ __forceinline__ unsigned short f2bf_u(float x) {
    __hip_bfloat16 h = __float2bfloat16(x);   // RNE
    return __builtin_bit_cast(unsigned short, h);
}
__device__ __forceinline__ float softplus_fast(float x) {
    return x > 20.f ? x : log1pf(__expf(x));
}
__device__ __forceinline__ float softplus_ref(float x) {
    return x > 20.f ? x : log1pf(expf(x));
}

// pi(k): contraction-position permutation letting the previous layer's
// C-layout registers feed the next MFMA's B positions with zero cross-lane
// movement (verified absmax 0.0 in R4/R5/R6).
__device__ __forceinline__ int kperm(int k) {
    return 4 * (k >> 3) + (k & 3) + 16 * ((k >> 2) & 1);
}

// A-frag weight prep (one 64-thread block, runs once per launch). RNE.
extern "C" __global__ void hib_prep(const float* __restrict__ W1,
                                    const float* __restrict__ W2,
                                    const float* __restrict__ Wmu,
                                    const float* __restrict__ Wv,
                                    unsigned short* __restrict__ wf)
{
    const int l = threadIdx.x;         // 0..63
    const int r = l & 15, kb = l >> 4;
#pragma unroll
    for (int j = 0; j < 8; j++) {
        const int k1 = kb * 8 + j;
        const int kp = kperm(k1);
        wf[(0 * 64 + l) * 8 + j] = f2bf_u(W1[k1 * 32 + r]);
        wf[(1 * 64 + l) * 8 + j] = f2bf_u(W1[k1 * 32 + 16 + r]);
        wf[(2 * 64 + l) * 8 + j] = f2bf_u(W2[kp * 32 + r]);
        wf[(3 * 64 + l) * 8 + j] = f2bf_u(W2[kp * 32 + 16 + r]);
        wf[(4 * 64 + l) * 8 + j] = f2bf_u(r < 8 ? Wmu[kp * 8 + r]
                                                : Wv[kp * 8 + (r - 8)]);
    }
}

// relu + RNE-pack two C-frags into the next layer's B-frag (pure per-lane).
// Scalar casts: compiler fuses pairs into v_cvt_pk_bf16_f32 (m240: don't
// hand-write). RNE verified exact (absmax 0.0) in R5/R6; truncation-pack
// was 3 ulp off (R7) — systematic bias accumulates over the N-sum.
__device__ __forceinline__ bf16x8 pack_relu(f32x4 a, f32x4 b) {
    bf16x8 o;
    o[0] = (short)f2bf_u(fmaxf(a[0], 0.f));
    o[1] = (short)f2bf_u(fmaxf(a[1], 0.f));
    o[2] = (short)f2bf_u(fmaxf(a[2], 0.f));
    o[3] = (short)f2bf_u(fmaxf(a[3], 0.f));
    o[4] = (short)f2bf_u(fmaxf(b[0], 0.f));
    o[5] = (short)f2bf_u(fmaxf(b[1], 0.f));
    o[6] = (short)f2bf_u(fmaxf(b[2], 0.f));
    o[7] = (short)f2bf_u(fmaxf(b[3], 0.f));
    return o;
}

__device__ __forceinline__ void red16(f32x4& v) {
#pragma unroll
    for (int off = 8; off; off >>= 1) {
        v[0] += __shfl_down(v[0], off);
        v[1] += __shfl_down(v[1], off);
        v[2] += __shfl_down(v[2], off);
        v[3] += __shfl_down(v[3], off);
    }
}

// direct global->LDS, 16B per lane; dst is wave-uniform base (lane*16 implicit)
__device__ __forceinline__ void gload_lds16(const float4* gsrc, float* ldst) {
    __builtin_amdgcn_global_load_lds(
        (const __attribute__((address_space(1))) unsigned int*)gsrc,
        (__attribute__((address_space(3))) unsigned int*)ldst,
        16, 0, 0);
}

__global__ void __launch_bounds__(256, 4)
hib_mfma(const float* __restrict__ batch,
         const int* __restrict__ labels,
         const float* __restrict__ eps1, const float* __restrict__ eps2,
         const unsigned short* __restrict__ wf,
         const float* __restrict__ b1, const float* __restrict__ b2,
         const float* __restrict__ bmu, const float* __restrict__ bv,
         const float* __restrict__ sw, const float* __restrict__ sb,
         float* __restrict__ out)
{
    __shared__ float lds[32 * ROWF];   // [feature row][128 pts x 2ch + pad]
    __shared__ float sacc[32];

    const int tid = threadIdx.x;
    const int b   = blockIdx.x;
    const int wid = tid >> 6, l = tid & 63;
    const int c   = l & 15, kb = l >> 4;

    if (tid < 32) sacc[tid] = 0.f;

    // weight A-frags, register-resident
    const bf16x8* wfv = (const bf16x8*)wf;
    const bf16x8 A1a = wfv[0 * 64 + l], A1b = wfv[1 * 64 + l];
    const bf16x8 A2a = wfv[2 * 64 + l], A2b = wfv[3 * 64 + l];
    const bf16x8 Ahd = wfv[4 * 64 + l];

    const int r4 = 4 * kb;
    const bool is_v = (kb >= 2);
    const int  z4   = 4 * (kb & 1);
    f32x4 c1a, c1b, c2a, c2b, chd;
    c1a[0] = b1[r4];      c1a[1] = b1[r4 + 1];      c1a[2] = b1[r4 + 2];      c1a[3] = b1[r4 + 3];
    c1b[0] = b1[16 + r4]; c1b[1] = b1[16 + r4 + 1]; c1b[2] = b1[16 + r4 + 2]; c1b[3] = b1[16 + r4 + 3];
    c2a[0] = b2[r4];      c2a[1] = b2[r4 + 1];      c2a[2] = b2[r4 + 2];      c2a[3] = b2[r4 + 3];
    c2b[0] = b2[16 + r4]; c2b[1] = b2[16 + r4 + 1]; c2b[2] = b2[16 + r4 + 2]; c2b[3] = b2[16 + r4 + 3];
    if (is_v) { chd[0] = bv[z4];  chd[1] = bv[z4 + 1];  chd[2] = bv[z4 + 2];  chd[3] = bv[z4 + 3]; }
    else      { chd[0] = bmu[z4]; chd[1] = bmu[z4 + 1]; chd[2] = bmu[z4 + 2]; chd[3] = bmu[z4 + 3]; }

    f32x4 acc0 = {0.f, 0.f, 0.f, 0.f};
    f32x4 acc1 = {0.f, 0.f, 0.f, 0.f};

    // batch[b] as float4: row r has 512 float4 (1024 pts x 2 ch)
    const float4* bp4 = (const float4*)batch + (size_t)b * 32 * 512;

#pragma unroll 1
    for (int st = 0; st < NSTG; st++) {
        // ---- stage load: one 1KB-contiguous global->LDS instr per row ----
#pragma unroll
        for (int q = 0; q < 8; q++) {
            const int r = wid * 8 + q;
            gload_lds16(bp4 + (size_t)r * 512 + st * 64 + l, &lds[r * ROWF]);
        }
        __syncthreads();   // drains vmcnt: stage resident

        // ---- compute: wave wid owns 32 pts x 2 ch = 4 frags x 16 cols ----
        f32x4 xq[8];
#pragma unroll
        for (int j = 0; j < 8; j++)
            xq[j] = *(const f32x4*)&lds[(kb * 8 + j) * ROWF + wid * 64 + c * 4];

        // stage A: RNE-pack all 4 B-frags (f: 0=p0c0, 1=p0c1, 2=p1c0, 3=p1c1)
        bf16x8 bw[4];
#pragma unroll
        for (int f = 0; f < 4; f++) {
            bf16x8 t;
#pragma unroll
            for (int j = 0; j < 8; j++) t[j] = (short)f2bf_u(xq[j][f]);
            bw[f] = t;
        }

        // stage B: 8 independent L1 MFMAs
        f32x4 d1a[4], d1b[4];
#pragma unroll
        for (int f = 0; f < 4; f++) {
            d1a[f] = __builtin_amdgcn_mfma_f32_16x16x32_bf16(A1a, bw[f], c1a, 0, 0, 0);
            d1b[f] = __builtin_amdgcn_mfma_f32_16x16x32_bf16(A1b, bw[f], c1b, 0, 0, 0);
        }

        // stage C: pack
        bf16x8 p2[4];
#pragma unroll
        for (int f = 0; f < 4; f++) p2[f] = pack_relu(d1a[f], d1b[f]);

        // stage D: 8 independent L2 MFMAs
        f32x4 d2a[4], d2b[4];
#pragma unroll
        for (int f = 0; f < 4; f++) {
            d2a[f] = __builtin_amdgcn_mfma_f32_16x16x32_bf16(A2a, p2[f], c2a, 0, 0, 0);
            d2b[f] = __builtin_amdgcn_mfma_f32_16x16x32_bf16(A2b, p2[f], c2b, 0, 0, 0);
        }

        // stage E: pack
        bf16x8 p3[4];
#pragma unroll
        for (int f = 0; f < 4; f++) p3[f] = pack_relu(d2a[f], d2b[f]);

        // stage F+G: 4 head MFMAs + accumulate
#pragma unroll
        for (int f = 0; f < 4; f++) {
            f32x4 e = __builtin_amdgcn_mfma_f32_16x16x32_bf16(Ahd, p3[f], chd, 0, 0, 0);
            f32x4& acc = (f & 1) ? acc1 : acc0;
            if (!is_v) {
                acc[0] += e[0]; acc[1] += e[1]; acc[2] += e[2]; acc[3] += e[3];
            } else {
                acc[0] += 1.f / fmaxf(softplus_fast(e[0]), VAR_MIN);
                acc[1] += 1.f / fmaxf(softplus_fast(e[1]), VAR_MIN);
                acc[2] += 1.f / fmaxf(softplus_fast(e[2]), VAR_MIN);
                acc[3] += 1.f / fmaxf(softplus_fast(e[3]), VAR_MIN);
            }
        }
        __syncthreads();   // stage buffer free for overwrite
    }

    // ---- reduce over the 16 point-columns in each lane group ----
    red16(acc0);
    red16(acc1);

    if (c == 0) {
        const int base = (is_v ? 16 : 0) + z4;   // +0: ch0, +8: ch1
        atomicAdd(&sacc[base + 0],     acc0[0]);
        atomicAdd(&sacc[base + 1],     acc0[1]);
        atomicAdd(&sacc[base + 2],     acc0[2]);
        atomicAdd(&sacc[base + 3],     acc0[3]);
        atomicAdd(&sacc[base + 8 + 0], acc1[0]);
        atomicAdd(&sacc[base + 8 + 1], acc1[1]);
        atomicAdd(&sacc[base + 8 + 2], acc1[2]);
        atomicAdd(&sacc[base + 8 + 3], acc1[3]);
    }
    __syncthreads();

    // ---- per-b tail on wave 0: pooling, KL, S x S sampled loss ----
    if (tid < 64) {
        const float a    = softplus_ref(sw[0]);
        const float sbv_ = sb[0];

        float muA[8], muB[8], sgA[8], sgB[8];
#pragma unroll
        for (int z = 0; z < 8; z++) {
            muA[z] = sacc[z];
            muB[z] = sacc[8 + z];
            sgA[z] = sqrtf(1.0f / sacc[16 + z]);
            sgB[z] = sqrtf(1.0f / sacc[24 + z]);
        }
        const int i = tid >> 3, j = tid & 7;
        float d2 = 0.f;
#pragma unroll
        for (int z = 0; z < 8; z++) {
            float e1 = eps1[((size_t)b * 8 + i) * 8 + z];
            float e2 = eps2[((size_t)b * 8 + j) * 8 + z];
            float zz1 = fmaf(sgA[z], e1, muA[z]);
            float zz2 = fmaf(sgB[z], e2, muB[z]);
            float d = zz1 - zz2;
            d2 = fmaf(d, d, d2);
        }
        const float lab = (float)labels[b];
        float contrib = softplus_ref(a * sqrtf(d2) - sbv_) * lab
                      * (1.0f / (64.0f * (float)B_));

        if (tid < 16) {
            const int cc = tid >> 3, z = tid & 7;
            float iv  = sacc[16 + cc * 8 + z];
            float var = 1.0f / iv;
            float m   = sacc[cc * 8 + z];
            contrib += (-0.5f * logf(var) + 0.5f * (var + m * m) - 0.5f)
                       * (BETA / (8.0f * (float)B_));
        }
#pragma unroll
        for (int off = 32; off; off >>= 1) contrib += __shfl_down(contrib, off);
        if (tid == 0) atomicAdd(out, contrib);
    }
}

extern "C" void kernel_launch(void* const* d_in, const int* in_sizes, int n_in,
                              void* d_out, int out_size, void* d_ws, size_t ws_size,
                              hipStream_t stream)
{
    (void)in_sizes; (void)n_in; (void)out_size; (void)ws_size;
    const float* batch  = (const float*)d_in[0];
    const int*   labels = (const int*)  d_in[1];
    const float* eps1   = (const float*)d_in[2];
    const float* eps2   = (const float*)d_in[3];
    const float* W1     = (const float*)d_in[4];
    const float* b1     = (const float*)d_in[5];
    const float* W2     = (const float*)d_in[6];
    const float* b2     = (const float*)d_in[7];
    const float* Wmu    = (const float*)d_in[8];
    const float* bmu    = (const float*)d_in[9];
    const float* Wv     = (const float*)d_in[10];
    const float* bv     = (const float*)d_in[11];
    const float* sw     = (const float*)d_in[12];
    const float* sb     = (const float*)d_in[13];

    unsigned short* wf = (unsigned short*)d_ws;  // 5 frags x 64 lanes x 8 bf16

    hipMemsetAsync(d_out, 0, sizeof(float), stream);
    hib_prep<<<1, 64, 0, stream>>>(W1, W2, Wmu, Wv, wf);
    hib_mfma<<<B_, 256, 0, stream>>>(batch, labels, eps1, eps2, wf,
                                     b1, b2, bmu, bv, sw, sb, (float*)d_out);
}

// Round 9
// 136.464 us; speedup vs baseline: 2.2252x; 1.9621x over previous
//
#include <hip/hip_runtime.h>
#include <hip/hip_bf16.h>

#define B_   2048
#define N_   1024
#define BETA 0.001f
#define VAR_MIN 1e-7f

#define PTS   64
#define NSTG  (N_ / PTS)       // 16 stages
#define RF    128              // floats per LDS row (64 pts x 2ch); NO pad — rows
                               // contiguous so one 1KB global_load_lds spans 2 rows

typedef __attribute__((ext_vector_type(8))) short  bf16x8;
typedef __attribute__((ext_vector_type(4))) float  f32x4;

__device__ __forceinline__ unsigned short f2bf_u(float x) {
    __hip_bfloat16 h = __float2bfloat16(x);   // RNE
    return __builtin_bit_cast(unsigned short, h);
}
// hot-path softplus: 2 HW transcendentals (v_exp_f32 + v_log_f32) instead of
// libm log1pf (~30+ instr). x<-16: 1+e^x rounds to 1 -> sp=0 -> VAR_MIN clamp,
// matching the reference's own max(var, VAR_MIN) clamp.
__device__ __forceinline__ float softplus_cheap(float x) {
    float sp = __logf(1.f + __expf(x));
    return x > 15.f ? x : sp;
}
__device__ __forceinline__ float rcp_fast(float x) {
    return __builtin_amdgcn_rcpf(x);          // v_rcp_f32, ~1 ulp
}
// accurate softplus for the tiny per-b tail only
__device__ __forceinline__ float softplus_ref(float x) {
    return x > 20.f ? x : log1pf(expf(x));
}

// pi(k): contraction-position permutation letting the previous layer's
// C-layout registers feed the next MFMA's B positions with zero cross-lane
// movement (verified absmax 0.0 in R4/R5/R6/R8).
__device__ __forceinline__ int kperm(int k) {
    return 4 * (k >> 3) + (k & 3) + 16 * ((k >> 2) & 1);
}

// A-frag weight prep (one 64-thread block). RNE.
extern "C" __global__ void hib_prep(const float* __restrict__ W1,
                                    const float* __restrict__ W2,
                                    const float* __restrict__ Wmu,
                                    const float* __restrict__ Wv,
                                    unsigned short* __restrict__ wf)
{
    const int l = threadIdx.x;         // 0..63
    const int r = l & 15, kb = l >> 4;
#pragma unroll
    for (int j = 0; j < 8; j++) {
        const int k1 = kb * 8 + j;
        const int kp = kperm(k1);
        wf[(0 * 64 + l) * 8 + j] = f2bf_u(W1[k1 * 32 + r]);
        wf[(1 * 64 + l) * 8 + j] = f2bf_u(W1[k1 * 32 + 16 + r]);
        wf[(2 * 64 + l) * 8 + j] = f2bf_u(W2[kp * 32 + r]);
        wf[(3 * 64 + l) * 8 + j] = f2bf_u(W2[kp * 32 + 16 + r]);
        wf[(4 * 64 + l) * 8 + j] = f2bf_u(r < 8 ? Wmu[kp * 8 + r]
                                                : Wv[kp * 8 + (r - 8)]);
    }
}

// relu + RNE-pack two C-frags into the next layer's B-frag (pure per-lane)
__device__ __forceinline__ bf16x8 pack_relu(f32x4 a, f32x4 b) {
    bf16x8 o;
    o[0] = (short)f2bf_u(fmaxf(a[0], 0.f));
    o[1] = (short)f2bf_u(fmaxf(a[1], 0.f));
    o[2] = (short)f2bf_u(fmaxf(a[2], 0.f));
    o[3] = (short)f2bf_u(fmaxf(a[3], 0.f));
    o[4] = (short)f2bf_u(fmaxf(b[0], 0.f));
    o[5] = (short)f2bf_u(fmaxf(b[1], 0.f));
    o[6] = (short)f2bf_u(fmaxf(b[2], 0.f));
    o[7] = (short)f2bf_u(fmaxf(b[3], 0.f));
    return o;
}

__device__ __forceinline__ void red16(f32x4& v) {
#pragma unroll
    for (int off = 8; off; off >>= 1) {
        v[0] += __shfl_down(v[0], off);
        v[1] += __shfl_down(v[1], off);
        v[2] += __shfl_down(v[2], off);
        v[3] += __shfl_down(v[3], off);
    }
}

// issue one stage's global->LDS loads for this wave (4 x 1KB instrs, each
// covering 2 feature-rows: per-lane global addrs, wave-uniform LDS base)
__device__ __forceinline__ void stage_issue(const float* __restrict__ bbase,
                                            float* __restrict__ ldsbuf,
                                            int st, int wid, int l)
{
    const int sub = l >> 5, lo = l & 31;
#pragma unroll
    for (int q = 0; q < 4; ++q) {
        const int row = wid * 8 + q * 2;
        const float* gs = bbase + (size_t)(row + sub) * (2 * N_) + st * RF + lo * 4;
        __builtin_amdgcn_global_load_lds(
            (const __attribute__((address_space(1))) unsigned int*)gs,
            (__attribute__((address_space(3))) unsigned int*)&ldsbuf[row * RF],
            16, 0, 0);
    }
}

__global__ void __launch_bounds__(256, 4)
hib_mfma(const float* __restrict__ batch,
         const int* __restrict__ labels,
         const float* __restrict__ eps1, const float* __restrict__ eps2,
         const unsigned short* __restrict__ wf,
         const float* __restrict__ b1, const float* __restrict__ b2,
         const float* __restrict__ bmu, const float* __restrict__ bv,
         const float* __restrict__ sw, const float* __restrict__ sb,
         float* __restrict__ out)
{
    __shared__ float lds[2][32 * RF];   // double-buffered 64-pt stages (32KB)
    __shared__ float sacc[32];

    const int tid = threadIdx.x;
    const int b   = blockIdx.x;
    const int wid = tid >> 6, l = tid & 63;
    const int c   = l & 15, kb = l >> 4;

    if (tid < 32) sacc[tid] = 0.f;

    // weight A-frags, register-resident
    const bf16x8* wfv = (const bf16x8*)wf;
    const bf16x8 A1a = wfv[0 * 64 + l], A1b = wfv[1 * 64 + l];
    const bf16x8 A2a = wfv[2 * 64 + l], A2b = wfv[3 * 64 + l];
    const bf16x8 Ahd = wfv[4 * 64 + l];

    const int r4 = 4 * kb;
    const bool is_v = (kb >= 2);
    const int  z4   = 4 * (kb & 1);
    f32x4 c1a, c1b, c2a, c2b, chd;
    c1a[0] = b1[r4];      c1a[1] = b1[r4 + 1];      c1a[2] = b1[r4 + 2];      c1a[3] = b1[r4 + 3];
    c1b[0] = b1[16 + r4]; c1b[1] = b1[16 + r4 + 1]; c1b[2] = b1[16 + r4 + 2]; c1b[3] = b1[16 + r4 + 3];
    c2a[0] = b2[r4];      c2a[1] = b2[r4 + 1];      c2a[2] = b2[r4 + 2];      c2a[3] = b2[r4 + 3];
    c2b[0] = b2[16 + r4]; c2b[1] = b2[16 + r4 + 1]; c2b[2] = b2[16 + r4 + 2]; c2b[3] = b2[16 + r4 + 3];
    if (is_v) { chd[0] = bv[z4];  chd[1] = bv[z4 + 1];  chd[2] = bv[z4 + 2];  chd[3] = bv[z4 + 3]; }
    else      { chd[0] = bmu[z4]; chd[1] = bmu[z4 + 1]; chd[2] = bmu[z4 + 2]; chd[3] = bmu[z4 + 3]; }

    f32x4 acc0 = {0.f, 0.f, 0.f, 0.f};
    f32x4 acc1 = {0.f, 0.f, 0.f, 0.f};

    const float* bbase = batch + (size_t)b * 32 * (2 * N_);

    // prologue: stage 0 in flight, drained by the barrier
    stage_issue(bbase, lds[0], 0, wid, l);
    __syncthreads();

    int buf = 0;
#pragma unroll 1
    for (int t = 0; t < NSTG; ++t) {
        // prefetch next stage into the other buffer; flies under compute
        if (t + 1 < NSTG)
            stage_issue(bbase, lds[buf ^ 1], t + 1, wid, l);

        // ---- compute from lds[buf]: this wave's 16 points x 2 channels ----
        float2 xr[8];
#pragma unroll
        for (int j = 0; j < 8; j++)
            xr[j] = *(const float2*)&lds[buf][(kb * 8 + j) * RF + (wid * 16 + c) * 2];

        bf16x8 f0, f1;
#pragma unroll
        for (int j = 0; j < 8; j++) {
            f0[j] = (short)f2bf_u(xr[j].x);
            f1[j] = (short)f2bf_u(xr[j].y);
        }

        f32x4 d1a0 = __builtin_amdgcn_mfma_f32_16x16x32_bf16(A1a, f0, c1a, 0, 0, 0);
        f32x4 d1b0 = __builtin_amdgcn_mfma_f32_16x16x32_bf16(A1b, f0, c1b, 0, 0, 0);
        f32x4 d1a1 = __builtin_amdgcn_mfma_f32_16x16x32_bf16(A1a, f1, c1a, 0, 0, 0);
        f32x4 d1b1 = __builtin_amdgcn_mfma_f32_16x16x32_bf16(A1b, f1, c1b, 0, 0, 0);

        bf16x8 p20 = pack_relu(d1a0, d1b0);
        bf16x8 p21 = pack_relu(d1a1, d1b1);

        f32x4 d2a0 = __builtin_amdgcn_mfma_f32_16x16x32_bf16(A2a, p20, c2a, 0, 0, 0);
        f32x4 d2b0 = __builtin_amdgcn_mfma_f32_16x16x32_bf16(A2b, p20, c2b, 0, 0, 0);
        f32x4 d2a1 = __builtin_amdgcn_mfma_f32_16x16x32_bf16(A2a, p21, c2a, 0, 0, 0);
        f32x4 d2b1 = __builtin_amdgcn_mfma_f32_16x16x32_bf16(A2b, p21, c2b, 0, 0, 0);

        bf16x8 p30 = pack_relu(d2a0, d2b0);
        bf16x8 p31 = pack_relu(d2a1, d2b1);

        f32x4 e0 = __builtin_amdgcn_mfma_f32_16x16x32_bf16(Ahd, p30, chd, 0, 0, 0);
        f32x4 e1 = __builtin_amdgcn_mfma_f32_16x16x32_bf16(Ahd, p31, chd, 0, 0, 0);

        if (!is_v) {
            acc0[0] += e0[0]; acc0[1] += e0[1]; acc0[2] += e0[2]; acc0[3] += e0[3];
            acc1[0] += e1[0]; acc1[1] += e1[1]; acc1[2] += e1[2]; acc1[3] += e1[3];
        } else {
            acc0[0] += rcp_fast(fmaxf(softplus_cheap(e0[0]), VAR_MIN));
            acc0[1] += rcp_fast(fmaxf(softplus_cheap(e0[1]), VAR_MIN));
            acc0[2] += rcp_fast(fmaxf(softplus_cheap(e0[2]), VAR_MIN));
            acc0[3] += rcp_fast(fmaxf(softplus_cheap(e0[3]), VAR_MIN));
            acc1[0] += rcp_fast(fmaxf(softplus_cheap(e1[0]), VAR_MIN));
            acc1[1] += rcp_fast(fmaxf(softplus_cheap(e1[1]), VAR_MIN));
            acc1[2] += rcp_fast(fmaxf(softplus_cheap(e1[2]), VAR_MIN));
            acc1[3] += rcp_fast(fmaxf(softplus_cheap(e1[3]), VAR_MIN));
        }

        __syncthreads();   // drains prefetch (vmcnt) + all reads of lds[buf]
        buf ^= 1;
    }

    // ---- reduce over the 16 point-columns in each lane group ----
    red16(acc0);
    red16(acc1);

    if (c == 0) {
        const int base = (is_v ? 16 : 0) + z4;   // +0: ch0, +8: ch1
        atomicAdd(&sacc[base + 0],     acc0[0]);
        atomicAdd(&sacc[base + 1],     acc0[1]);
        atomicAdd(&sacc[base + 2],     acc0[2]);
        atomicAdd(&sacc[base + 3],     acc0[3]);
        atomicAdd(&sacc[base + 8 + 0], acc1[0]);
        atomicAdd(&sacc[base + 8 + 1], acc1[1]);
        atomicAdd(&sacc[base + 8 + 2], acc1[2]);
        atomicAdd(&sacc[base + 8 + 3], acc1[3]);
    }
    __syncthreads();

    // ---- per-b tail on wave 0: pooling, KL, S x S sampled loss ----
    if (tid < 64) {
        const float a    = softplus_ref(sw[0]);
        const float sbv_ = sb[0];

        float muA[8], muB[8], sgA[8], sgB[8];
#pragma unroll
        for (int z = 0; z < 8; z++) {
            muA[z] = sacc[z];
            muB[z] = sacc[8 + z];
            sgA[z] = sqrtf(1.0f / sacc[16 + z]);
            sgB[z] = sqrtf(1.0f / sacc[24 + z]);
        }
        const int i = tid >> 3, j = tid & 7;
        float d2 = 0.f;
#pragma unroll
        for (int z = 0; z < 8; z++) {
            float e1 = eps1[((size_t)b * 8 + i) * 8 + z];
            float e2 = eps2[((size_t)b * 8 + j) * 8 + z];
            float zz1 = fmaf(sgA[z], e1, muA[z]);
            float zz2 = fmaf(sgB[z], e2, muB[z]);
            float d = zz1 - zz2;
            d2 = fmaf(d, d, d2);
        }
        const float lab = (float)labels[b];
        float contrib = softplus_ref(a * sqrtf(d2) - sbv_) * lab
                      * (1.0f / (64.0f * (float)B_));

        if (tid < 16) {
            const int cc = tid >> 3, z = tid & 7;
            float iv  = sacc[16 + cc * 8 + z];
            float var = 1.0f / iv;
            float m   = sacc[cc * 8 + z];
            contrib += (-0.5f * logf(var) + 0.5f * (var + m * m) - 0.5f)
                       * (BETA / (8.0f * (float)B_));
        }
#pragma unroll
        for (int off = 32; off; off >>= 1) contrib += __shfl_down(contrib, off);
        if (tid == 0) atomicAdd(out, contrib);
    }
}

extern "C" void kernel_launch(void* const* d_in, const int* in_sizes, int n_in,
                              void* d_out, int out_size, void* d_ws, size_t ws_size,
                              hipStream_t stream)
{
    (void)in_sizes; (void)n_in; (void)out_size; (void)ws_size;
    const float* batch  = (const float*)d_in[0];
    const int*   labels = (const int*)  d_in[1];
    const float* eps1   = (const float*)d_in[2];
    const float* eps2   = (const float*)d_in[3];
    const float* W1     = (const float*)d_in[4];
    const float* b1     = (const float*)d_in[5];
    const float* W2     = (const float*)d_in[6];
    const float* b2     = (const float*)d_in[7];
    const float* Wmu    = (const float*)d_in[8];
    const float* bmu    = (const float*)d_in[9];
    const float* Wv     = (const float*)d_in[10];
    const float* bv     = (const float*)d_in[11];
    const float* sw     = (const float*)d_in[12];
    const float* sb     = (const float*)d_in[13];

    unsigned short* wf = (unsigned short*)d_ws;  // 5 frags x 64 lanes x 8 bf16

    hipMemsetAsync(d_out, 0, sizeof(float), stream);
    hib_prep<<<1, 64, 0, stream>>>(W1, W2, Wmu, Wv, wf);
    hib_mfma<<<B_, 256, 0, stream>>>(batch, labels, eps1, eps2, wf,
                                     b1, b2, bmu, bv, sw, sb, (float*)d_out);
}